// Round 2
// baseline (341.100 us; speedup 1.0000x reference)
//
#include <hip/hip_runtime.h>

#define BB   256
#define NIN  1152
#define OO   10
#define IL   8
#define OL   16
#define EPSQ 1e-7f

// Lane mapping: 4 lanes per b; lane-quad index q = t&3 owns k = 4q..4q+3.
// 64 b's per block. w loads are float4 (16B/lane); routing reduce is an
// in-lane dot4 + 2-step shfl_xor over the 4-lane group.
__global__ __launch_bounds__(256) void caps_partial(
    const float* __restrict__ x,       // [B][NIN][IL]
    const float* __restrict__ w,       // [NIN][O][IL][OL]
    const float* __restrict__ vsum,    // [B][O][OL] or null
    float* __restrict__ partial,       // [B][nch][O][OL]
    int nper, int nch)
{
    const int t = threadIdx.x;
    const int q = t & 3;               // k-quad
    const int g = t >> 2;              // 0..63: b within block
    const int b = blockIdx.x * 64 + g;
    const int chunk = blockIdx.y;
    const int n0 = chunk * nper;

    const bool uniform = (vsum == nullptr);
    float4 vs[OO];
    if (!uniform) {
        #pragma unroll
        for (int o = 0; o < OO; ++o)
            vs[o] = *reinterpret_cast<const float4*>(vsum + ((size_t)b * OO + o) * OL + q * 4);
    }

    float4 sp[OO];
    #pragma unroll
    for (int o = 0; o < OO; ++o) sp[o] = make_float4(0.f, 0.f, 0.f, 0.f);

    for (int nn = 0; nn < nper; ++nn) {
        const int n = n0 + nn;
        const float4* xp = reinterpret_cast<const float4*>(x + ((size_t)b * NIN + n) * IL);
        const float4 xa = xp[0];
        const float4 xc = xp[1];
        const float xv[IL] = {xa.x, xa.y, xa.z, xa.w, xc.x, xc.y, xc.z, xc.w};

        // w as float4 array; element offset (o*8+i)*16 + q*4 -> float4 idx (o*8+i)*4 + q
        const float4* wp = reinterpret_cast<const float4*>(w + (size_t)n * OO * IL * OL) + q;

        float4 u[OO];
        #pragma unroll
        for (int o = 0; o < OO; ++o) {
            float4 acc = make_float4(0.f, 0.f, 0.f, 0.f);
            #pragma unroll
            for (int i = 0; i < IL; ++i) {
                const float4 wv = wp[(o * IL + i) * 4];
                acc.x = fmaf(wv.x, xv[i], acc.x);
                acc.y = fmaf(wv.y, xv[i], acc.y);
                acc.z = fmaf(wv.z, xv[i], acc.z);
                acc.w = fmaf(wv.w, xv[i], acc.w);
            }
            u[o] = acc;
        }

        if (uniform) {
            #pragma unroll
            for (int o = 0; o < OO; ++o) {
                sp[o].x += u[o].x; sp[o].y += u[o].y;
                sp[o].z += u[o].z; sp[o].w += u[o].w;
            }
        } else {
            float bij[OO];
            #pragma unroll
            for (int o = 0; o < OO; ++o) {
                float d = u[o].x * vs[o].x;
                d = fmaf(u[o].y, vs[o].y, d);
                d = fmaf(u[o].z, vs[o].z, d);
                d = fmaf(u[o].w, vs[o].w, d);
                d += __shfl_xor(d, 1, 4);
                d += __shfl_xor(d, 2, 4);
                bij[o] = d;
            }
            float m = bij[0];
            #pragma unroll
            for (int o = 1; o < OO; ++o) m = fmaxf(m, bij[o]);
            float e[OO];
            float se = 0.f;
            #pragma unroll
            for (int o = 0; o < OO; ++o) { e[o] = __expf(bij[o] - m); se += e[o]; }
            const float r = 1.f / se;
            #pragma unroll
            for (int o = 0; o < OO; ++o) {
                const float c = e[o] * r;
                sp[o].x = fmaf(c, u[o].x, sp[o].x);
                sp[o].y = fmaf(c, u[o].y, sp[o].y);
                sp[o].z = fmaf(c, u[o].z, sp[o].z);
                sp[o].w = fmaf(c, u[o].w, sp[o].w);
            }
        }
    }

    const float scale = uniform ? (1.f / OO) : 1.f;
    #pragma unroll
    for (int o = 0; o < OO; ++o) {
        float4 v = sp[o];
        v.x *= scale; v.y *= scale; v.z *= scale; v.w *= scale;
        *reinterpret_cast<float4*>(partial + (((size_t)b * nch + chunk) * OO + o) * OL + q * 4) = v;
    }
}

__global__ __launch_bounds__(192) void caps_reduce_squash(
    const float* __restrict__ partial,  // [B][nch][O][OL]
    const float* __restrict__ bias,     // [O][OL]
    const float* __restrict__ prevAdd,  // [B][O][OL] or null
    float* __restrict__ out,            // [B][O][OL]
    int nch)
{
    const int t = threadIdx.x;
    if (t >= OO * OL) return;
    const int b = blockIdx.x;

    // 4-way accumulator ILP over the chunk-sum
    float s0 = bias[t], s1 = 0.f, s2 = 0.f, s3 = 0.f;
    const float* p = partial + (size_t)b * nch * OO * OL + t;
    int ch = 0;
    for (; ch + 4 <= nch; ch += 4) {
        s0 += p[(size_t)(ch + 0) * OO * OL];
        s1 += p[(size_t)(ch + 1) * OO * OL];
        s2 += p[(size_t)(ch + 2) * OO * OL];
        s3 += p[(size_t)(ch + 3) * OO * OL];
    }
    for (; ch < nch; ++ch) s0 += p[(size_t)ch * OO * OL];
    float s = (s0 + s1) + (s2 + s3);

    float d = s * s;
    #pragma unroll
    for (int off = 8; off >= 1; off >>= 1)
        d += __shfl_xor(d, off, 16);

    const float f = d / ((1.f + d) * sqrtf(d + EPSQ));
    float v = f * s;
    if (prevAdd) v += prevAdd[(size_t)b * OO * OL + t];
    out[(size_t)b * OO * OL + t] = v;
}

extern "C" void kernel_launch(void* const* d_in, const int* in_sizes, int n_in,
                              void* d_out, int out_size, void* d_ws, size_t ws_size,
                              hipStream_t stream) {
    const float* x    = (const float*)d_in[0]; // (B, NIN, 8, 1)
    const float* w    = (const float*)d_in[1]; // (1, NIN, O, 8, 16)
    const float* bias = (const float*)d_in[2]; // (1, 1, O, 16, 1)
    float* out = (float*)d_out;                // (B, 1, O, 16, 1)

    // pick the largest chunk count that fits the workspace
    int nch = 36;
    const size_t vbytes = (size_t)BB * OO * OL * sizeof(float);
    for (int cand : {144, 72}) {
        size_t need = (size_t)BB * cand * OO * OL * sizeof(float) + 2 * vbytes;
        if (need <= ws_size) { nch = cand; break; }
    }
    const int nper = NIN / nch;

    float* partial = (float*)d_ws;                            // B*nch*160
    float* v0      = partial + (size_t)BB * nch * OO * OL;    // B*160
    float* vsb     = v0 + (size_t)BB * OO * OL;               // B*160

    const dim3 pgrid(BB / 64, nch);
    const dim3 pblk(256);

    // iter 0: uniform c, produce v0
    caps_partial<<<pgrid, pblk, 0, stream>>>(x, w, nullptr, partial, nper, nch);
    caps_reduce_squash<<<BB, 192, 0, stream>>>(partial, bias, nullptr, v0, nch);
    // iter 1: c = softmax(u.v0), produce vsb = v0 + v1
    caps_partial<<<pgrid, pblk, 0, stream>>>(x, w, v0, partial, nper, nch);
    caps_reduce_squash<<<BB, 192, 0, stream>>>(partial, bias, v0, vsb, nch);
    // iter 2: c = softmax(u.(v0+v1)), final v -> d_out
    caps_partial<<<pgrid, pblk, 0, stream>>>(x, w, vsb, partial, nper, nch);
    caps_reduce_squash<<<BB, 192, 0, stream>>>(partial, bias, nullptr, out, nch);
}

// Round 3
// 116.396 us; speedup vs baseline: 2.9305x; 2.9305x over previous
//
#include <hip/hip_runtime.h>

#define BB   256
#define NIN  1152
#define OO   10
#define IL   8
#define OL   16
#define ROW  (OO*OL)      // 160
#define EPSQ 1e-7f
#define NCH  144
#define NPER 8            // NIN/NCH

typedef unsigned short ushx8 __attribute__((ext_vector_type(8)));
typedef unsigned short ushx4 __attribute__((ext_vector_type(4)));

__device__ __forceinline__ unsigned short f2bf(float f) {
    unsigned u = __builtin_bit_cast(unsigned, f);
    u += 0x7FFFu + ((u >> 16) & 1u);   // RNE
    return (unsigned short)(u >> 16);
}
__device__ __forceinline__ float bf2f(unsigned short h) {
    unsigned u = ((unsigned)h) << 16;
    return __builtin_bit_cast(float, u);
}

// K2: build u_hat[bl][n][o*16+k] in bf16. Grid: NIN blocks. Block: 192
// (threads 0..159 = one (o,k) each; w coeffs live in registers; x is
// wave-uniform -> s_load; stores coalesced 2B*160).
__global__ __launch_bounds__(192) void caps_build(
    const float* __restrict__ x, const float* __restrict__ w,
    unsigned short* __restrict__ u, int b0, int Bc)
{
    const int t = threadIdx.x;
    if (t >= ROW) return;
    const int n = blockIdx.x;
    const int o = t >> 4;
    const int k = t & 15;

    float wr[IL];
    #pragma unroll
    for (int i = 0; i < IL; ++i)
        wr[i] = w[(size_t)n * (OO * IL * OL) + (o * IL + i) * OL + k];

    unsigned short* up = u + (size_t)n * ROW + t;
    const float* xb = x + ((size_t)b0 * NIN + n) * IL;

    #pragma unroll 4
    for (int bl = 0; bl < Bc; ++bl) {
        const float* xp = xb + (size_t)bl * (NIN * IL);  // uniform -> s_load
        float s = 0.f;
        #pragma unroll
        for (int i = 0; i < IL; ++i) s = fmaf(wr[i], xp[i], s);
        up[(size_t)bl * ((size_t)NIN * ROW)] = f2bf(s);
    }
}

// K3: iter0 — s0[b,o,k] = 0.1*sum_n u + bias, squash -> v0. Grid: Bc blocks.
__global__ __launch_bounds__(256) void caps_iter0(
    const unsigned short* __restrict__ u, const float* __restrict__ bias,
    float* __restrict__ v0)
{
    __shared__ float red[12][ROW];
    const int t = threadIdx.x;
    const int bl = blockIdx.x;
    if (t < 240) {
        const int c = t % 20;   // 16B chunk within the 320B row
        const int j = t / 20;   // n-lane 0..11
        const ushx8* base = reinterpret_cast<const ushx8*>(u + (size_t)bl * NIN * ROW);
        float acc[8] = {0.f,0.f,0.f,0.f,0.f,0.f,0.f,0.f};
        for (int m = 0; m < 96; m += 4) {
            const size_t n0 = (size_t)(j + 12 * m);
            ushx8 a0 = base[(n0)      * 20 + c];
            ushx8 a1 = base[(n0 + 12) * 20 + c];
            ushx8 a2 = base[(n0 + 24) * 20 + c];
            ushx8 a3 = base[(n0 + 36) * 20 + c];
            #pragma unroll
            for (int e = 0; e < 8; ++e)
                acc[e] += (bf2f(a0[e]) + bf2f(a1[e])) + (bf2f(a2[e]) + bf2f(a3[e]));
        }
        #pragma unroll
        for (int e = 0; e < 8; ++e) red[j][c * 8 + e] = acc[e];
    }
    __syncthreads();
    if (t < ROW) {
        float s = 0.f;
        #pragma unroll
        for (int j = 0; j < 12; ++j) s += red[j][t];
        s = s * 0.1f + bias[t];
        float d = s * s;
        d += __shfl_xor(d, 1, 16);
        d += __shfl_xor(d, 2, 16);
        d += __shfl_xor(d, 4, 16);
        d += __shfl_xor(d, 8, 16);
        const float f = d / ((1.f + d) * sqrtf(d + EPSQ));
        v0[(size_t)bl * ROW + t] = f * s;
    }
}

// K4: one routing iteration over materialized u_hat. 4 lanes per b (k-quads),
// 64 b per 256-thread block. Grid (Bc/64, NCH).
__global__ __launch_bounds__(256) void caps_iter(
    const unsigned short* __restrict__ u, const float* __restrict__ vsum,
    float* __restrict__ partial)
{
    const int t = threadIdx.x;
    const int q = t & 3;
    const int g = t >> 2;
    const int bl = blockIdx.x * (blockDim.x >> 2) + g;
    const int chunk = blockIdx.y;

    float4 vs[OO];
    #pragma unroll
    for (int o = 0; o < OO; ++o)
        vs[o] = *reinterpret_cast<const float4*>(vsum + (size_t)bl * ROW + o * OL + q * 4);

    float4 sp[OO];
    #pragma unroll
    for (int o = 0; o < OO; ++o) sp[o] = make_float4(0.f, 0.f, 0.f, 0.f);

    const unsigned short* ub = u + ((size_t)bl * NIN + (size_t)chunk * NPER) * ROW;
    for (int nn = 0; nn < NPER; ++nn) {
        const unsigned short* un = ub + (size_t)nn * ROW;
        ushx4 raw[OO];
        #pragma unroll
        for (int o = 0; o < OO; ++o)
            raw[o] = *reinterpret_cast<const ushx4*>(un + o * OL + q * 4);

        float bij[OO];
        #pragma unroll
        for (int o = 0; o < OO; ++o) {
            float d = bf2f(raw[o][0]) * vs[o].x;
            d = fmaf(bf2f(raw[o][1]), vs[o].y, d);
            d = fmaf(bf2f(raw[o][2]), vs[o].z, d);
            d = fmaf(bf2f(raw[o][3]), vs[o].w, d);
            d += __shfl_xor(d, 1, 4);
            d += __shfl_xor(d, 2, 4);
            bij[o] = d;
        }
        float m = bij[0];
        #pragma unroll
        for (int o = 1; o < OO; ++o) m = fmaxf(m, bij[o]);
        float e[OO], se = 0.f;
        #pragma unroll
        for (int o = 0; o < OO; ++o) { e[o] = __expf(bij[o] - m); se += e[o]; }
        const float r = 1.f / se;
        #pragma unroll
        for (int o = 0; o < OO; ++o) {
            const float c = e[o] * r;
            sp[o].x = fmaf(c, bf2f(raw[o][0]), sp[o].x);
            sp[o].y = fmaf(c, bf2f(raw[o][1]), sp[o].y);
            sp[o].z = fmaf(c, bf2f(raw[o][2]), sp[o].z);
            sp[o].w = fmaf(c, bf2f(raw[o][3]), sp[o].w);
        }
    }
    float* pp = partial + ((size_t)bl * NCH + chunk) * ROW + q * 4;
    #pragma unroll
    for (int o = 0; o < OO; ++o)
        *reinterpret_cast<float4*>(pp + o * OL) = sp[o];
}

// K5: sum partials over chunks + bias, squash; optional prevAdd (v running sum).
__global__ __launch_bounds__(192) void caps_reduce_squash(
    const float* __restrict__ partial, const float* __restrict__ bias,
    const float* __restrict__ prevAdd, float* __restrict__ out)
{
    const int t = threadIdx.x;
    if (t >= ROW) return;
    const int bl = blockIdx.x;

    float s0 = bias[t], s1 = 0.f, s2 = 0.f, s3 = 0.f;
    const float* p = partial + (size_t)bl * NCH * ROW + t;
    for (int ch = 0; ch < NCH; ch += 4) {
        s0 += p[(size_t)(ch + 0) * ROW];
        s1 += p[(size_t)(ch + 1) * ROW];
        s2 += p[(size_t)(ch + 2) * ROW];
        s3 += p[(size_t)(ch + 3) * ROW];
    }
    float s = (s0 + s1) + (s2 + s3);

    float d = s * s;
    d += __shfl_xor(d, 1, 16);
    d += __shfl_xor(d, 2, 16);
    d += __shfl_xor(d, 4, 16);
    d += __shfl_xor(d, 8, 16);
    const float f = d / ((1.f + d) * sqrtf(d + EPSQ));
    float v = f * s;
    if (prevAdd) v += prevAdd[(size_t)bl * ROW + t];
    out[(size_t)bl * ROW + t] = v;
}

extern "C" void kernel_launch(void* const* d_in, const int* in_sizes, int n_in,
                              void* d_out, int out_size, void* d_ws, size_t ws_size,
                              hipStream_t stream) {
    const float* x    = (const float*)d_in[0]; // (B, NIN, 8, 1)
    const float* w    = (const float*)d_in[1]; // (1, NIN, O, 8, 16)
    const float* bias = (const float*)d_in[2]; // (1, 1, O, 16, 1)
    float* out = (float*)d_out;                // (B, 1, O, 16, 1)

    // per-b workspace: u_hat bf16 + fp32 chunk-partials + 2 v-buffers
    const size_t per_b = (size_t)NIN * ROW * 2 + (size_t)NCH * ROW * 4 + 2 * ROW * 4;
    int Bc = 256;
    while (Bc > 32 && (size_t)Bc * per_b > ws_size) Bc >>= 1;

    unsigned short* u  = (unsigned short*)d_ws;
    float* partial = (float*)((char*)d_ws + (size_t)Bc * NIN * ROW * 2);
    float* v0  = partial + (size_t)Bc * NCH * ROW;
    float* vsb = v0 + (size_t)Bc * ROW;

    const int gb  = (Bc >= 64) ? Bc / 64 : 1;
    const int th4 = ((Bc >= 64) ? 64 : Bc) * 4;
    const dim3 g4(gb, NCH);

    for (int b0 = 0; b0 < BB; b0 += Bc) {
        caps_build<<<NIN, 192, 0, stream>>>(x, w, u, b0, Bc);
        caps_iter0<<<Bc, 256, 0, stream>>>(u, bias, v0);
        caps_iter<<<g4, th4, 0, stream>>>(u, v0, partial);
        caps_reduce_squash<<<Bc, 192, 0, stream>>>(partial, bias, v0, vsb);
        caps_iter<<<g4, th4, 0, stream>>>(u, vsb, partial);
        caps_reduce_squash<<<Bc, 192, 0, stream>>>(partial, bias, nullptr,
                                                   out + (size_t)b0 * ROW);
    }
}